// Round 8
// baseline (147.617 us; speedup 1.0000x reference)
//
#include <hip/hip_runtime.h>
#include <hip/hip_bf16.h>
#include <cstdint>

typedef __attribute__((ext_vector_type(8))) __bf16 bf16x8;
typedef __attribute__((ext_vector_type(4))) float f32x4;
typedef unsigned short u16;
typedef unsigned int u32;

struct alignas(8) U16x4 { u16 x, y, z, w; };
struct alignas(8) U32x2 { u32 x, y; };

__device__ __forceinline__ u16 f2b(float x) {
    u32 u = __builtin_bit_cast(u32, x);
    u += 0x7fffu + ((u >> 16) & 1u);   // round-to-nearest-even
    return (u16)(u >> 16);
}
__device__ __forceinline__ u32 cvtpk(float lo, float hi) {
    u32 r;
    asm("v_cvt_pk_bf16_f32 %0, %1, %2" : "=v"(r) : "v"(lo), "v"(hi));
    return r;
}

// ---------------- kernel 1: f32 -> bf16 convert (hidden + concat weights) ----
__global__ __launch_bounds__(256) void cvt_kernel(
    const float* __restrict__ hs,
    const float* __restrict__ wq, const float* __restrict__ wk, const float* __restrict__ wv,
    u16* __restrict__ hsb, u16* __restrict__ wb)
{
    int i = blockIdx.x * 256 + threadIdx.x;       // float4 chunk index, exact grid
    const float4* src; u16* dst; int off;
    if (i < 1048576) { src = (const float4*)hs; dst = hsb; off = i; }
    else {
        int j = i - 1048576;                      // 3 * 262144 chunks
        int w = j >> 18;
        int o = j & 262143;
        src = (const float4*)(w == 0 ? wq : (w == 1 ? wk : wv));
        dst = wb + w * 1048576;
        off = o;
    }
    float4 v = src[off];
    U16x4 r; r.x = f2b(v.x); r.y = f2b(v.y); r.z = f2b(v.z); r.w = f2b(v.w);
    *(U16x4*)(dst + off * 4) = r;
}

// ---------------- kernel 2: QKV GEMM  C[4096,3072] = A[4096,1024] * W[3072,1024]^T
// Round-8: BK=32 + DOUBLE-BUFFERED global_load_lds staging (attn-proven 2-phase:
// issue next tile's STAGE before compute, single vmcnt(0)-drain barrier per iter).
// BK=32 makes the LINEAR LDS layout bank-optimal: row stride 64 B adds
// (row&1)*16 to the bank index, so (g, c-parity) tiles all 32 banks at the
// ds_read_b128 floor -- no swizzle needed (BK=64's 128 B stride was 2x worse).
__global__ __launch_bounds__(256, 3) void qkv_gemm(
    const u16* __restrict__ A, const u16* __restrict__ W,
    const float* __restrict__ bq, const float* __restrict__ bk, const float* __restrict__ bv,
    u16* __restrict__ Qo, u16* __restrict__ Ko, u16* __restrict__ Vt)
{
    __shared__ u16 As[2][128 * 32];   // 8 KB per buffer
    __shared__ u16 Bs[2][128 * 32];
    const int tid = threadIdx.x;
    const int lane = tid & 63, wid = tid >> 6;
    const int wr = (wid >> 1) * 64, wc = (wid & 1) * 64;  // wave sub-tile origin
    const int g = lane >> 4, c = lane & 15;

    // 768 blocks: XCD-bijective remap; within an XCD bn varies slowly -> 3 W-panels
    // (768 KB) L2-resident per XCD.
    int lin = blockIdx.y * 24 + blockIdx.x;
    int wg = (lin & 7) * 96 + (lin >> 3);
    const int bn = wg >> 5;      // 0..23
    const int bm = wg & 31;      // 0..31

    f32x4 acc[4][4] = {};

    // stage one 128x32 K-slice of A and W into buffer bf (512 chunks of 16B each)
#define GSTAGE(bf, k0)                                                              \
    {                                                                               \
        _Pragma("unroll") for (int i = 0; i < 2; ++i) {                             \
            int chunk = i * 256 + tid;                                              \
            int row = chunk >> 2, col = (chunk & 3) * 8;                            \
            const u16* ga = A + (bm * 128 + row) * 1024 + (k0) + col;               \
            const u16* gb = W + (bn * 128 + row) * 1024 + (k0) + col;               \
            u16* la = &As[bf][0] + (i * 256 + wid * 64) * 8;                        \
            u16* lb = &Bs[bf][0] + (i * 256 + wid * 64) * 8;                        \
            __builtin_amdgcn_global_load_lds((const __attribute__((address_space(1))) u32*)ga, \
                                             (__attribute__((address_space(3))) u32*)la, 16, 0, 0); \
            __builtin_amdgcn_global_load_lds((const __attribute__((address_space(1))) u32*)gb, \
                                             (__attribute__((address_space(3))) u32*)lb, 16, 0, 0); \
        }                                                                           \
    }

    GSTAGE(0, 0);
    __syncthreads();                  // vmcnt(0) drain: slice 0 ready

    int cur = 0;
    for (int t = 0; t < 32; ++t) {
        if (t < 31) GSTAGE(cur ^ 1, (t + 1) * 32);   // async, lands by next barrier
        bf16x8 af[4], bf4[4];
        #pragma unroll
        for (int i = 0; i < 4; ++i)
            af[i] = *(const bf16x8*)(&As[cur][0] + (wr + i * 16 + c) * 32 + g * 8);
        #pragma unroll
        for (int j = 0; j < 4; ++j)
            bf4[j] = *(const bf16x8*)(&Bs[cur][0] + (wc + j * 16 + c) * 32 + g * 8);
        #pragma unroll
        for (int i = 0; i < 4; ++i)
            #pragma unroll
            for (int j = 0; j < 4; ++j)
                acc[i][j] = __builtin_amdgcn_mfma_f32_16x16x32_bf16(af[i], bf4[j], acc[i][j], 0, 0, 0);
        __syncthreads();              // all reads of cur done; next slice drained
        cur ^= 1;
    }
#undef GSTAGE

    const int region = bn >> 3;                      // 0=Q 1=K 2=V
    const float* bias = region == 0 ? bq : (region == 1 ? bk : bv);
    #pragma unroll
    for (int i = 0; i < 4; ++i) {
        int m0 = bm * 128 + wr + i * 16 + g * 4;     // output row base (4 rows)
        int b = m0 >> 10, s0 = m0 & 1023;
        #pragma unroll
        for (int j = 0; j < 4; ++j) {
            int n = (bn & 7) * 128 + wc + j * 16 + c;  // col within region [0,1024)
            float bb = bias[n];
            int h = n >> 6, d = n & 63;
            int bh = b * 16 + h;
            if (region == 2) {
                U16x4 pk;
                pk.x = f2b(acc[i][j][0] + bb);
                pk.y = f2b(acc[i][j][1] + bb);
                pk.z = f2b(acc[i][j][2] + bb);
                pk.w = f2b(acc[i][j][3] + bb);
                *(U16x4*)(Vt + (bh * 64 + d) * 1024 + s0) = pk;   // s0 % 4 == 0
            } else if (region == 1) {
                #pragma unroll
                for (int r = 0; r < 4; ++r)
                    Ko[(bh * 1024 + s0 + r) * 64 + d] = f2b(acc[i][j][r] + bb);
            } else {
                #pragma unroll
                for (int r = 0; r < 4; ++r)           // fold 1/sqrt(D)=0.125 into Q (exact pow2)
                    Qo[(bh * 1024 + s0 + r) * 64 + d] = f2b((acc[i][j][r] + bb) * 0.125f);
            }
        }
    }
}

// ---------------- kernel 3: fused attention, post-softmax multiplicative link mask
// Round-8: drop V staging (mistake #7 / m169: K/V are L2-resident at S=1024) --
// V fragments loaded per-wave direct from global, issued at tile-top so their
// ~200-400 cy latency hides under the QK+exp phase (4 waves/SIMD TLP). K stays
// LDS-staged (shared by 4 waves), double-buffered, both-sides XOR swizzle.
// P per wave, stride 64 + XOR bank swizzle. LDS 24 KB. 1024 blocks x 4 waves.
// No online max: scores are O(10), exp() safe in f32; denom reduced at the end.
__global__ __launch_bounds__(256, 4) void attn_kernel(
    const u16* __restrict__ Q, const u16* __restrict__ K, const u16* __restrict__ Vt,
    const float* __restrict__ amask, const float* __restrict__ link,
    float* __restrict__ out)
{
    __shared__ u16 Ks[2][64 * 64];     // 8 KB per buffer
    __shared__ u16 P[4][16 * 64];      // per-wave [q=16][k=64], XOR-swizzled banks
    const int tid = threadIdx.x;
    const int lane = tid & 63, wid = tid >> 6;
    const int g = lane >> 4, c = lane & 15;
    const int c7 = c & 7;

    // XCD swizzle: 1024 blocks; XCD x owns logical x*128..x*128+127 = half a
    // batch's q-range (512 q-rows, 2 MB link slice) across all 16 heads.
    int hw = blockIdx.x;
    int logical = (hw & 7) * 128 + (hw >> 3);
    int b = logical >> 8;              // [0,4)
    int qt = (logical >> 4) & 15;      // [0,16) tiles of 64 q-rows
    int h = logical & 15;
    int bh = b * 16 + h;
    const int qbase = qt * 64 + wid * 16;

    const u16* Qh = Q + bh * 65536;
    const u16* Kh = K + bh * 65536;
    const u16* Vh = Vt + bh * 65536;
    const float* mk = amask + b * 1024;
    const float* lkq = link + (size_t)b * 1048576 + (size_t)(qbase + c) * 1024;

    bf16x8 qfx0 = *(const bf16x8*)(Qh + (qbase + c) * 64 + g * 8);
    bf16x8 qfx1 = *(const bf16x8*)(Qh + (qbase + c) * 64 + 32 + g * 8);

    float lsum = 0.f;
    f32x4 ctx[4] = {};
    u16* const Pb = &P[wid][0];

    // stage K kv-tile into buffer bf: 512 chunks of 16B. Source chunk-in-row is
    // XOR-swizzled so LDS stays linear (rule #21); K rows are 128 B -> needs it.
#define ASTAGE(bf, kv)                                                              \
    {                                                                               \
        _Pragma("unroll") for (int i = 0; i < 2; ++i) {                             \
            int chunk = i * 256 + tid;                                              \
            int row = chunk >> 3;                                                   \
            int scir = (chunk & 7) ^ (row & 7);                                     \
            const u16* gk = Kh + ((kv) + row) * 64 + scir * 8;                      \
            u16* lk = &Ks[bf][0] + (i * 256 + wid * 64) * 8;                        \
            __builtin_amdgcn_global_load_lds((const __attribute__((address_space(1))) u32*)gk, \
                                             (__attribute__((address_space(3))) u32*)lk, 16, 0, 0); \
        }                                                                           \
    }

    ASTAGE(0, 0);
    __syncthreads();                   // vmcnt(0) drain: tile 0 ready

    int cur = 0;
    for (int t = 0; t < 16; ++t) {
        if (t < 15) ASTAGE(cur ^ 1, (t + 1) * 64);  // async, lands by next barrier
        const int kv = t * 64;
        const u16* Kb = &Ks[cur][0];

        // hoist this tile's V fragments (global, L2-resident) + mask + link:
        // all independent of the QK chain, latency hides under QK + exp.
        bf16x8 vv[8];
        #pragma unroll
        for (int dt = 0; dt < 4; ++dt)
            #pragma unroll
            for (int kk = 0; kk < 2; ++kk)
                vv[dt * 2 + kk] = *(const bf16x8*)(Vh + (dt * 16 + c) * 1024 + kv + kk * 32 + g * 8);
        f32x4 m4[4], lk4[4];
        #pragma unroll
        for (int kt = 0; kt < 4; ++kt) {
            m4[kt]  = *(const f32x4*)(mk  + kv + kt * 16 + g * 4);
            lk4[kt] = *(const f32x4*)(lkq + kv + kt * 16 + g * 4);
        }

        // ---- QK^T + exp + link, one 16-key group at a time ----
        #pragma unroll
        for (int kt = 0; kt < 4; ++kt) {
            bf16x8 kf0 = *(const bf16x8*)(Kb + (kt * 16 + c) * 64 + ((g)     ^ c7) * 8);
            bf16x8 kf1 = *(const bf16x8*)(Kb + (kt * 16 + c) * 64 + ((4 + g) ^ c7) * 8);
            f32x4 sc = {};
            sc = __builtin_amdgcn_mfma_f32_16x16x32_bf16(kf0, qfx0, sc, 0, 0, 0);
            sc = __builtin_amdgcn_mfma_f32_16x16x32_bf16(kf1, qfx1, sc, 0, 0, 0);
            float e0 = __expf(sc[0] + m4[kt][0]);
            float e1 = __expf(sc[1] + m4[kt][1]);
            float e2 = __expf(sc[2] + m4[kt][2]);
            float e3 = __expf(sc[3] + m4[kt][3]);
            lsum += (e0 + e1) + (e2 + e3);
            U32x2 pw;
            pw.x = cvtpk(e0 * lk4[kt][0], e1 * lk4[kt][1]);
            pw.y = cvtpk(e2 * lk4[kt][2], e3 * lk4[kt][3]);
            // P write: row c, 8B-chunk (kt*4+g) ^ ((c&7)<<1)  [bank-uniform]
            *(U32x2*)(Pb + c * 64 + (((kt * 4 + g) ^ (c7 << 1)) * 4)) = pw;
        }
        // ---- PV: P from per-wave LDS (in-order DS pipe), V already in regs ----
        __builtin_amdgcn_s_setprio(1);
        #pragma unroll
        for (int kk = 0; kk < 2; ++kk) {
            // P read: row c, 16B pair starting at chunk (kk*8+g*2) ^ ((c&7)<<1)
            bf16x8 pf = *(const bf16x8*)(Pb + c * 64 + (((kk * 8 + g * 2) ^ (c7 << 1)) * 4));
            #pragma unroll
            for (int dt = 0; dt < 4; ++dt)
                ctx[dt] = __builtin_amdgcn_mfma_f32_16x16x32_bf16(pf, vv[dt * 2 + kk], ctx[dt], 0, 0, 0);
        }
        __builtin_amdgcn_s_setprio(0);
        __syncthreads();               // all reads of Ks[cur] done; stage drained
        cur ^= 1;
    }
#undef ASTAGE

    lsum += __shfl_xor(lsum, 16, 64);
    lsum += __shfl_xor(lsum, 32, 64);

    #pragma unroll
    for (int r = 0; r < 4; ++r) {
        float inv = 1.0f / __shfl(lsum, g * 4 + r, 16);
        int q = qbase + g * 4 + r;
        float* orow = out + (size_t)b * 1048576 + (size_t)q * 1024 + h * 64;
        #pragma unroll
        for (int dt = 0; dt < 4; ++dt)
            orow[dt * 16 + c] = ctx[dt][r] * inv;
    }
}

extern "C" void kernel_launch(void* const* d_in, const int* in_sizes, int n_in,
                              void* d_out, int out_size, void* d_ws, size_t ws_size,
                              hipStream_t stream)
{
    (void)in_sizes; (void)n_in; (void)out_size; (void)ws_size;
    const float* hs    = (const float*)d_in[0];
    const float* amask = (const float*)d_in[1];
    const float* link  = (const float*)d_in[2];
    const float* Wq    = (const float*)d_in[3];
    const float* bq    = (const float*)d_in[4];
    const float* Wk    = (const float*)d_in[5];
    const float* bk    = (const float*)d_in[6];
    const float* Wv    = (const float*)d_in[7];
    const float* bv    = (const float*)d_in[8];
    float* out = (float*)d_out;

    char* ws = (char*)d_ws;
    u16* hsb = (u16*)ws;                   // 8 MiB  [4096][1024] bf16
    u16* wb  = (u16*)(ws + (8u  << 20));   // 6 MiB  [3072][1024] bf16 (Wq|Wk|Wv)
    u16* Qb  = (u16*)(ws + (14u << 20));   // 8 MiB  [B,H,S,64]  (pre-scaled by 0.125)
    u16* Kb  = (u16*)(ws + (22u << 20));   // 8 MiB  [B,H,S,64]
    u16* Vtb = (u16*)(ws + (30u << 20));   // 8 MiB  [B,H,64,S]

    cvt_kernel<<<7168, 256, 0, stream>>>(hs, Wq, Wk, Wv, hsb, wb);
    qkv_gemm<<<dim3(24, 32), 256, 0, stream>>>(hsb, wb, bq, bk, bv, Qb, Kb, Vtb);
    attn_kernel<<<1024, 256, 0, stream>>>(Qb, Kb, Vtb, amask, link, out);
}

// Round 9
// 126.044 us; speedup vs baseline: 1.1712x; 1.1712x over previous
//
#include <hip/hip_runtime.h>
#include <hip/hip_bf16.h>
#include <cstdint>

typedef __attribute__((ext_vector_type(8))) __bf16 bf16x8;
typedef __attribute__((ext_vector_type(4))) float f32x4;
typedef unsigned short u16;
typedef unsigned int u32;

struct alignas(8) U16x4 { u16 x, y, z, w; };
struct alignas(8) U32x2 { u32 x, y; };

__device__ __forceinline__ u16 f2b(float x) {
    u32 u = __builtin_bit_cast(u32, x);
    u += 0x7fffu + ((u >> 16) & 1u);   // round-to-nearest-even
    return (u16)(u >> 16);
}
__device__ __forceinline__ u32 cvtpk(float lo, float hi) {
    u32 r;
    asm("v_cvt_pk_bf16_f32 %0, %1, %2" : "=v"(r) : "v"(lo), "v"(hi));
    return r;
}

// ---------------- kernel 1: f32 -> bf16 convert (hidden + concat weights) ----
__global__ __launch_bounds__(256) void cvt_kernel(
    const float* __restrict__ hs,
    const float* __restrict__ wq, const float* __restrict__ wk, const float* __restrict__ wv,
    u16* __restrict__ hsb, u16* __restrict__ wb)
{
    int i = blockIdx.x * 256 + threadIdx.x;       // float4 chunk index, exact grid
    const float4* src; u16* dst; int off;
    if (i < 1048576) { src = (const float4*)hs; dst = hsb; off = i; }
    else {
        int j = i - 1048576;                      // 3 * 262144 chunks
        int w = j >> 18;
        int o = j & 262143;
        src = (const float4*)(w == 0 ? wq : (w == 1 ? wk : wv));
        dst = wb + w * 1048576;
        off = o;
    }
    float4 v = src[off];
    U16x4 r; r.x = f2b(v.x); r.y = f2b(v.y); r.z = f2b(v.z); r.w = f2b(v.w);
    *(U16x4*)(dst + off * 4) = r;
}

// ---------------- kernel 2: QKV GEMM  C[4096,3072] = A[4096,1024] * W[3072,1024]^T
// BK=32 + double-buffered global_load_lds staging (2-phase: issue next slice
// before compute, one vmcnt(0)-drain barrier per iter). BK=32 keeps the LINEAR
// LDS layout bank-optimal (row stride 64 B). Proven ~31 us in round 8.
__global__ __launch_bounds__(256, 3) void qkv_gemm(
    const u16* __restrict__ A, const u16* __restrict__ W,
    const float* __restrict__ bq, const float* __restrict__ bk, const float* __restrict__ bv,
    u16* __restrict__ Qo, u16* __restrict__ Ko, u16* __restrict__ Vt)
{
    __shared__ u16 As[2][128 * 32];   // 8 KB per buffer
    __shared__ u16 Bs[2][128 * 32];
    const int tid = threadIdx.x;
    const int lane = tid & 63, wid = tid >> 6;
    const int wr = (wid >> 1) * 64, wc = (wid & 1) * 64;  // wave sub-tile origin
    const int g = lane >> 4, c = lane & 15;

    // 768 blocks: XCD-bijective remap; within an XCD bn varies slowly -> 3 W-panels
    // (768 KB) L2-resident per XCD.
    int lin = blockIdx.y * 24 + blockIdx.x;
    int wg = (lin & 7) * 96 + (lin >> 3);
    const int bn = wg >> 5;      // 0..23
    const int bm = wg & 31;      // 0..31

    f32x4 acc[4][4] = {};

    // stage one 128x32 K-slice of A and W into buffer bf (512 chunks of 16B each)
#define GSTAGE(bf, k0)                                                              \
    {                                                                               \
        _Pragma("unroll") for (int i = 0; i < 2; ++i) {                             \
            int chunk = i * 256 + tid;                                              \
            int row = chunk >> 2, col = (chunk & 3) * 8;                            \
            const u16* ga = A + (bm * 128 + row) * 1024 + (k0) + col;               \
            const u16* gb = W + (bn * 128 + row) * 1024 + (k0) + col;               \
            u16* la = &As[bf][0] + (i * 256 + wid * 64) * 8;                        \
            u16* lb = &Bs[bf][0] + (i * 256 + wid * 64) * 8;                        \
            __builtin_amdgcn_global_load_lds((const __attribute__((address_space(1))) u32*)ga, \
                                             (__attribute__((address_space(3))) u32*)la, 16, 0, 0); \
            __builtin_amdgcn_global_load_lds((const __attribute__((address_space(1))) u32*)gb, \
                                             (__attribute__((address_space(3))) u32*)lb, 16, 0, 0); \
        }                                                                           \
    }

    GSTAGE(0, 0);
    __syncthreads();                  // vmcnt(0) drain: slice 0 ready

    int cur = 0;
    for (int t = 0; t < 32; ++t) {
        if (t < 31) GSTAGE(cur ^ 1, (t + 1) * 32);   // async, lands by next barrier
        bf16x8 af[4], bf4[4];
        #pragma unroll
        for (int i = 0; i < 4; ++i)
            af[i] = *(const bf16x8*)(&As[cur][0] + (wr + i * 16 + c) * 32 + g * 8);
        #pragma unroll
        for (int j = 0; j < 4; ++j)
            bf4[j] = *(const bf16x8*)(&Bs[cur][0] + (wc + j * 16 + c) * 32 + g * 8);
        #pragma unroll
        for (int i = 0; i < 4; ++i)
            #pragma unroll
            for (int j = 0; j < 4; ++j)
                acc[i][j] = __builtin_amdgcn_mfma_f32_16x16x32_bf16(af[i], bf4[j], acc[i][j], 0, 0, 0);
        __syncthreads();              // all reads of cur done; next slice drained
        cur ^= 1;
    }
#undef GSTAGE

    const int region = bn >> 3;                      // 0=Q 1=K 2=V
    const float* bias = region == 0 ? bq : (region == 1 ? bk : bv);
    #pragma unroll
    for (int i = 0; i < 4; ++i) {
        int m0 = bm * 128 + wr + i * 16 + g * 4;     // output row base (4 rows)
        int b = m0 >> 10, s0 = m0 & 1023;
        #pragma unroll
        for (int j = 0; j < 4; ++j) {
            int n = (bn & 7) * 128 + wc + j * 16 + c;  // col within region [0,1024)
            float bb = bias[n];
            int h = n >> 6, d = n & 63;
            int bh = b * 16 + h;
            if (region == 2) {
                U16x4 pk;
                pk.x = f2b(acc[i][j][0] + bb);
                pk.y = f2b(acc[i][j][1] + bb);
                pk.z = f2b(acc[i][j][2] + bb);
                pk.w = f2b(acc[i][j][3] + bb);
                *(U16x4*)(Vt + (bh * 64 + d) * 1024 + s0) = pk;   // s0 % 4 == 0
            } else if (region == 1) {
                #pragma unroll
                for (int r = 0; r < 4; ++r)
                    Ko[(bh * 1024 + s0 + r) * 64 + d] = f2b(acc[i][j][r] + bb);
            } else {
                #pragma unroll
                for (int r = 0; r < 4; ++r)           // fold 1/sqrt(D)=0.125 into Q (exact pow2)
                    Qo[(bh * 1024 + s0 + r) * 64 + d] = f2b((acc[i][j][r] + bb) * 0.125f);
            }
        }
    }
}

// ---------------- kernel 3: fused attention, post-softmax multiplicative link mask
// Round-9 = round-7 structure (best measured: K AND V LDS-staged double-buffered,
// P per-wave stride-64 XOR-swizzled, 40 KB LDS, 1024 blocks x 4 waves x 16 q-rows,
// 4 blocks/CU) + mask/link PREFETCH: the kv loop is 2x-unrolled with two named
// register sets (static indexing, rule #20) so tile t+1's 8x16B mask/link global
// loads are issued during tile t's compute instead of serially after the barrier
// (__syncthreads is a compiler memory fence -- no automatic hoist). Buffer parity
// is static: tile t uses Ks/Vs[t&1].
// No online max: scores are O(10), exp() safe in f32; denom reduced at the end.
__global__ __launch_bounds__(256, 4) void attn_kernel(
    const u16* __restrict__ Q, const u16* __restrict__ K, const u16* __restrict__ Vt,
    const float* __restrict__ amask, const float* __restrict__ link,
    float* __restrict__ out)
{
    __shared__ u16 Ks[2][64 * 64];     // 8 KB per buffer
    __shared__ u16 Vs[2][64 * 64];     // 8 KB per buffer
    __shared__ u16 P[4][16 * 64];      // per-wave [q=16][k=64], XOR-swizzled banks
    const int tid = threadIdx.x;
    const int lane = tid & 63, wid = tid >> 6;
    const int g = lane >> 4, c = lane & 15;
    const int c7 = c & 7;

    // XCD swizzle: 1024 blocks; XCD x owns logical x*128..x*128+127 = half a
    // batch's q-range (512 q-rows, 2 MB link slice) across all 16 heads.
    int hw = blockIdx.x;
    int logical = (hw & 7) * 128 + (hw >> 3);
    int b = logical >> 8;              // [0,4)
    int qt = (logical >> 4) & 15;      // [0,16) tiles of 64 q-rows
    int h = logical & 15;
    int bh = b * 16 + h;
    const int qbase = qt * 64 + wid * 16;

    const u16* Qh = Q + bh * 65536;
    const u16* Kh = K + bh * 65536;
    const u16* Vh = Vt + bh * 65536;
    const float* mk = amask + b * 1024;
    const float* lkq = link + (size_t)b * 1048576 + (size_t)(qbase + c) * 1024;

    bf16x8 qfx0 = *(const bf16x8*)(Qh + (qbase + c) * 64 + g * 8);
    bf16x8 qfx1 = *(const bf16x8*)(Qh + (qbase + c) * 64 + 32 + g * 8);

    float lsum = 0.f;
    f32x4 ctx[4] = {};
    u16* const Pb = &P[wid][0];

    // stage K+V kv-tile into buffer bf: 512+512 chunks of 16B. Source chunk-in-row
    // XOR-swizzled so LDS stays linear (rule #21); rows are 128 B -> needs it.
#define ASTAGE(bf, kv)                                                              \
    {                                                                               \
        _Pragma("unroll") for (int i = 0; i < 2; ++i) {                             \
            int chunk = i * 256 + tid;                                              \
            int row = chunk >> 3;                                                   \
            int scir = (chunk & 7) ^ (row & 7);                                     \
            const u16* gk = Kh + ((kv) + row) * 64 + scir * 8;                      \
            const u16* gv = Vh + row * 1024 + (kv) + scir * 8;                      \
            u16* lk = &Ks[bf][0] + (i * 256 + wid * 64) * 8;                        \
            u16* lv = &Vs[bf][0] + (i * 256 + wid * 64) * 8;                        \
            __builtin_amdgcn_global_load_lds((const __attribute__((address_space(1))) u32*)gk, \
                                             (__attribute__((address_space(3))) u32*)lk, 16, 0, 0); \
            __builtin_amdgcn_global_load_lds((const __attribute__((address_space(1))) u32*)gv, \
                                             (__attribute__((address_space(3))) u32*)lv, 16, 0, 0); \
        }                                                                           \
    }

#define LOADML(m4s, lk4s, kvo)                                                      \
    {                                                                               \
        _Pragma("unroll") for (int kt = 0; kt < 4; ++kt) {                          \
            m4s[kt]  = *(const f32x4*)(mk  + (kvo) + kt * 16 + g * 4);              \
            lk4s[kt] = *(const f32x4*)(lkq + (kvo) + kt * 16 + g * 4);              \
        }                                                                           \
    }

    // one kv-tile: QK^T + exp + link -> P (LDS), then PV from staged V
#define TILE(m4s, lk4s, kv, Kb, Vb)                                                 \
    {                                                                               \
        _Pragma("unroll") for (int kt = 0; kt < 4; ++kt) {                          \
            bf16x8 kf0 = *(const bf16x8*)((Kb) + (kt * 16 + c) * 64 + ((g)     ^ c7) * 8); \
            bf16x8 kf1 = *(const bf16x8*)((Kb) + (kt * 16 + c) * 64 + ((4 + g) ^ c7) * 8); \
            f32x4 sc = {};                                                          \
            sc = __builtin_amdgcn_mfma_f32_16x16x32_bf16(kf0, qfx0, sc, 0, 0, 0);   \
            sc = __builtin_amdgcn_mfma_f32_16x16x32_bf16(kf1, qfx1, sc, 0, 0, 0);   \
            float e0 = __expf(sc[0] + m4s[kt][0]);                                  \
            float e1 = __expf(sc[1] + m4s[kt][1]);                                  \
            float e2 = __expf(sc[2] + m4s[kt][2]);                                  \
            float e3 = __expf(sc[3] + m4s[kt][3]);                                  \
            lsum += (e0 + e1) + (e2 + e3);                                          \
            U32x2 pw;                                                               \
            pw.x = cvtpk(e0 * lk4s[kt][0], e1 * lk4s[kt][1]);                       \
            pw.y = cvtpk(e2 * lk4s[kt][2], e3 * lk4s[kt][3]);                       \
            *(U32x2*)(Pb + c * 64 + (((kt * 4 + g) ^ (c7 << 1)) * 4)) = pw;         \
        }                                                                           \
        __builtin_amdgcn_s_setprio(1);                                              \
        _Pragma("unroll") for (int kk = 0; kk < 2; ++kk) {                          \
            bf16x8 pf = *(const bf16x8*)(Pb + c * 64 + (((kk * 8 + g * 2) ^ (c7 << 1)) * 4)); \
            _Pragma("unroll") for (int dt = 0; dt < 4; ++dt) {                      \
                bf16x8 vf = *(const bf16x8*)((Vb) + (dt * 16 + c) * 64 + ((kk * 4 + g) ^ c7) * 8); \
                ctx[dt] = __builtin_amdgcn_mfma_f32_16x16x32_bf16(pf, vf, ctx[dt], 0, 0, 0); \
            }                                                                       \
        }                                                                           \
        __builtin_amdgcn_s_setprio(0);                                              \
    }

    f32x4 m4A[4], lk4A[4], m4B[4], lk4B[4];
    ASTAGE(0, 0);
    LOADML(m4A, lk4A, 0);
    __syncthreads();                   // vmcnt(0) drain: tile 0 ready

    for (int it = 0; it < 8; ++it) {
        const int t0 = it * 2, t1 = t0 + 1;
        // tile t0 (buffers [0]); prefetch stage(t1) + mask/link(t1) first
        ASTAGE(1, t1 * 64);
        LOADML(m4B, lk4B, t1 * 64);
        TILE(m4A, lk4A, t0 * 64, &Ks[0][0], &Vs[0][0]);
        __syncthreads();               // reads of buf0 done; buf1 stage drained

        // tile t1 (buffers [1]); prefetch stage(t1+1) + mask/link(t1+1)
        if (t1 < 15) {
            ASTAGE(0, (t1 + 1) * 64);
            LOADML(m4A, lk4A, (t1 + 1) * 64);
        }
        TILE(m4B, lk4B, t1 * 64, &Ks[1][0], &Vs[1][0]);
        __syncthreads();               // reads of buf1 done; buf0 stage drained
    }
#undef ASTAGE
#undef LOADML
#undef TILE

    lsum += __shfl_xor(lsum, 16, 64);
    lsum += __shfl_xor(lsum, 32, 64);

    #pragma unroll
    for (int r = 0; r < 4; ++r) {
        float inv = 1.0f / __shfl(lsum, g * 4 + r, 16);
        int q = qbase + g * 4 + r;
        float* orow = out + (size_t)b * 1048576 + (size_t)q * 1024 + h * 64;
        #pragma unroll
        for (int dt = 0; dt < 4; ++dt)
            orow[dt * 16 + c] = ctx[dt][r] * inv;
    }
}

extern "C" void kernel_launch(void* const* d_in, const int* in_sizes, int n_in,
                              void* d_out, int out_size, void* d_ws, size_t ws_size,
                              hipStream_t stream)
{
    (void)in_sizes; (void)n_in; (void)out_size; (void)ws_size;
    const float* hs    = (const float*)d_in[0];
    const float* amask = (const float*)d_in[1];
    const float* link  = (const float*)d_in[2];
    const float* Wq    = (const float*)d_in[3];
    const float* bq    = (const float*)d_in[4];
    const float* Wk    = (const float*)d_in[5];
    const float* bk    = (const float*)d_in[6];
    const float* Wv    = (const float*)d_in[7];
    const float* bv    = (const float*)d_in[8];
    float* out = (float*)d_out;

    char* ws = (char*)d_ws;
    u16* hsb = (u16*)ws;                   // 8 MiB  [4096][1024] bf16
    u16* wb  = (u16*)(ws + (8u  << 20));   // 6 MiB  [3072][1024] bf16 (Wq|Wk|Wv)
    u16* Qb  = (u16*)(ws + (14u << 20));   // 8 MiB  [B,H,S,64]  (pre-scaled by 0.125)
    u16* Kb  = (u16*)(ws + (22u << 20));   // 8 MiB  [B,H,S,64]
    u16* Vtb = (u16*)(ws + (30u << 20));   // 8 MiB  [B,H,64,S]

    cvt_kernel<<<7168, 256, 0, stream>>>(hs, Wq, Wk, Wv, hsb, wb);
    qkv_gemm<<<dim3(24, 32), 256, 0, stream>>>(hsb, wb, bq, bk, bv, Qb, Kb, Vtb);
    attn_kernel<<<1024, 256, 0, stream>>>(Qb, Kb, Vtb, amask, link, out);
}

// Round 10
// 97.667 us; speedup vs baseline: 1.5114x; 1.2906x over previous
//
#include <hip/hip_runtime.h>
#include <hip/hip_bf16.h>
#include <cstdint>

typedef __attribute__((ext_vector_type(8))) __bf16 bf16x8;
typedef __attribute__((ext_vector_type(4))) float f32x4;
typedef unsigned short u16;
typedef unsigned int u32;

struct alignas(8) U16x4 { u16 x, y, z, w; };
struct alignas(8) U32x2 { u32 x, y; };

__device__ __forceinline__ u16 f2b(float x) {
    u32 u = __builtin_bit_cast(u32, x);
    u += 0x7fffu + ((u >> 16) & 1u);   // round-to-nearest-even
    return (u16)(u >> 16);
}
__device__ __forceinline__ u32 cvtpk(float lo, float hi) {
    u32 r;
    asm("v_cvt_pk_bf16_f32 %0, %1, %2" : "=v"(r) : "v"(lo), "v"(hi));
    return r;
}

// ---------------- kernel 1: f32 -> bf16 convert (hidden + concat weights) ----
__global__ __launch_bounds__(256) void cvt_kernel(
    const float* __restrict__ hs,
    const float* __restrict__ wq, const float* __restrict__ wk, const float* __restrict__ wv,
    u16* __restrict__ hsb, u16* __restrict__ wb)
{
    int i = blockIdx.x * 256 + threadIdx.x;       // float4 chunk index, exact grid
    const float4* src; u16* dst; int off;
    if (i < 1048576) { src = (const float4*)hs; dst = hsb; off = i; }
    else {
        int j = i - 1048576;                      // 3 * 262144 chunks
        int w = j >> 18;
        int o = j & 262143;
        src = (const float4*)(w == 0 ? wq : (w == 1 ? wk : wv));
        dst = wb + w * 1048576;
        off = o;
    }
    float4 v = src[off];
    U16x4 r; r.x = f2b(v.x); r.y = f2b(v.y); r.z = f2b(v.z); r.w = f2b(v.w);
    *(U16x4*)(dst + off * 4) = r;
}

// ---------------- kernel 2: QKV GEMM  C[4096,3072] = A[4096,1024] * W[3072,1024]^T
// BK=32 + double-buffered global_load_lds staging (2-phase: issue next slice
// before compute, one vmcnt(0)-drain barrier per iter). BK=32 keeps the LINEAR
// LDS layout bank-optimal (row stride 64 B). Proven ~31 us in round 8.
__global__ __launch_bounds__(256, 3) void qkv_gemm(
    const u16* __restrict__ A, const u16* __restrict__ W,
    const float* __restrict__ bq, const float* __restrict__ bk, const float* __restrict__ bv,
    u16* __restrict__ Qo, u16* __restrict__ Ko, u16* __restrict__ Vt)
{
    __shared__ u16 As[2][128 * 32];   // 8 KB per buffer
    __shared__ u16 Bs[2][128 * 32];
    const int tid = threadIdx.x;
    const int lane = tid & 63, wid = tid >> 6;
    const int wr = (wid >> 1) * 64, wc = (wid & 1) * 64;  // wave sub-tile origin
    const int g = lane >> 4, c = lane & 15;

    // 768 blocks: XCD-bijective remap; within an XCD bn varies slowly -> 3 W-panels
    // (768 KB) L2-resident per XCD.
    int lin = blockIdx.y * 24 + blockIdx.x;
    int wg = (lin & 7) * 96 + (lin >> 3);
    const int bn = wg >> 5;      // 0..23
    const int bm = wg & 31;      // 0..31

    f32x4 acc[4][4] = {};

    // stage one 128x32 K-slice of A and W into buffer bf (512 chunks of 16B each)
#define GSTAGE(bf, k0)                                                              \
    {                                                                               \
        _Pragma("unroll") for (int i = 0; i < 2; ++i) {                             \
            int chunk = i * 256 + tid;                                              \
            int row = chunk >> 2, col = (chunk & 3) * 8;                            \
            const u16* ga = A + (bm * 128 + row) * 1024 + (k0) + col;               \
            const u16* gb = W + (bn * 128 + row) * 1024 + (k0) + col;               \
            u16* la = &As[bf][0] + (i * 256 + wid * 64) * 8;                        \
            u16* lb = &Bs[bf][0] + (i * 256 + wid * 64) * 8;                        \
            __builtin_amdgcn_global_load_lds((const __attribute__((address_space(1))) u32*)ga, \
                                             (__attribute__((address_space(3))) u32*)la, 16, 0, 0); \
            __builtin_amdgcn_global_load_lds((const __attribute__((address_space(1))) u32*)gb, \
                                             (__attribute__((address_space(3))) u32*)lb, 16, 0, 0); \
        }                                                                           \
    }

    GSTAGE(0, 0);
    __syncthreads();                  // vmcnt(0) drain: slice 0 ready

    int cur = 0;
    for (int t = 0; t < 32; ++t) {
        if (t < 31) GSTAGE(cur ^ 1, (t + 1) * 32);   // async, lands by next barrier
        bf16x8 af[4], bf4[4];
        #pragma unroll
        for (int i = 0; i < 4; ++i)
            af[i] = *(const bf16x8*)(&As[cur][0] + (wr + i * 16 + c) * 32 + g * 8);
        #pragma unroll
        for (int j = 0; j < 4; ++j)
            bf4[j] = *(const bf16x8*)(&Bs[cur][0] + (wc + j * 16 + c) * 32 + g * 8);
        #pragma unroll
        for (int i = 0; i < 4; ++i)
            #pragma unroll
            for (int j = 0; j < 4; ++j)
                acc[i][j] = __builtin_amdgcn_mfma_f32_16x16x32_bf16(af[i], bf4[j], acc[i][j], 0, 0, 0);
        __syncthreads();              // all reads of cur done; next slice drained
        cur ^= 1;
    }
#undef GSTAGE

    const int region = bn >> 3;                      // 0=Q 1=K 2=V
    const float* bias = region == 0 ? bq : (region == 1 ? bk : bv);
    #pragma unroll
    for (int i = 0; i < 4; ++i) {
        int m0 = bm * 128 + wr + i * 16 + g * 4;     // output row base (4 rows)
        int b = m0 >> 10, s0 = m0 & 1023;
        #pragma unroll
        for (int j = 0; j < 4; ++j) {
            int n = (bn & 7) * 128 + wc + j * 16 + c;  // col within region [0,1024)
            float bb = bias[n];
            int h = n >> 6, d = n & 63;
            int bh = b * 16 + h;
            if (region == 2) {
                U16x4 pk;
                pk.x = f2b(acc[i][j][0] + bb);
                pk.y = f2b(acc[i][j][1] + bb);
                pk.z = f2b(acc[i][j][2] + bb);
                pk.w = f2b(acc[i][j][3] + bb);
                *(U16x4*)(Vt + (bh * 64 + d) * 1024 + s0) = pk;   // s0 % 4 == 0
            } else if (region == 1) {
                #pragma unroll
                for (int r = 0; r < 4; ++r)
                    Ko[(bh * 1024 + s0 + r) * 64 + d] = f2b(acc[i][j][r] + bb);
            } else {
                #pragma unroll
                for (int r = 0; r < 4; ++r)           // fold 1/sqrt(D)=0.125 into Q (exact pow2)
                    Qo[(bh * 1024 + s0 + r) * 64 + d] = f2b((acc[i][j][r] + bb) * 0.125f);
            }
        }
    }
}

// ---------------- kernel 3: fused attention, post-softmax multiplicative link mask
// Round-7 verbatim (best measured: 61.8 us): K AND V LDS-staged double-buffered
// via async global_load_lds (both-sides XOR swizzle, rule #21), P per-wave
// stride-64 + XOR bank swizzle, LDS exactly 40 KB -> 4 blocks/CU (16 waves/CU).
// Mask/link loaded at tile top (NO cross-barrier register prefetch: round 9
// proved a second register set spills at the 64-VGPR budget -> 112 MB scratch).
// No online max: scores are O(10), exp() safe in f32; denom reduced at the end.
__global__ __launch_bounds__(256, 4) void attn_kernel(
    const u16* __restrict__ Q, const u16* __restrict__ K, const u16* __restrict__ Vt,
    const float* __restrict__ amask, const float* __restrict__ link,
    float* __restrict__ out)
{
    __shared__ u16 Ks[2][64 * 64];     // 8 KB per buffer
    __shared__ u16 Vs[2][64 * 64];     // 8 KB per buffer
    __shared__ u16 P[4][16 * 64];      // per-wave [q=16][k=64], XOR-swizzled banks
    const int tid = threadIdx.x;
    const int lane = tid & 63, wid = tid >> 6;
    const int g = lane >> 4, c = lane & 15;
    const int c7 = c & 7;

    // XCD swizzle: 1024 blocks; XCD x owns logical x*128..x*128+127 = half a
    // batch's q-range (512 q-rows, 2 MB link slice) across all 16 heads.
    int hw = blockIdx.x;
    int logical = (hw & 7) * 128 + (hw >> 3);
    int b = logical >> 8;              // [0,4)
    int qt = (logical >> 4) & 15;      // [0,16) tiles of 64 q-rows
    int h = logical & 15;
    int bh = b * 16 + h;
    const int qbase = qt * 64 + wid * 16;

    const u16* Qh = Q + bh * 65536;
    const u16* Kh = K + bh * 65536;
    const u16* Vh = Vt + bh * 65536;
    const float* mk = amask + b * 1024;
    const float* lkq = link + (size_t)b * 1048576 + (size_t)(qbase + c) * 1024;

    bf16x8 qfx0 = *(const bf16x8*)(Qh + (qbase + c) * 64 + g * 8);
    bf16x8 qfx1 = *(const bf16x8*)(Qh + (qbase + c) * 64 + 32 + g * 8);

    float lsum = 0.f;
    f32x4 ctx[4] = {};
    u16* const Pb = &P[wid][0];

    // stage K+V kv-tile into buffer bf: 512+512 chunks of 16B. Source chunk-in-row
    // XOR-swizzled so LDS stays linear (rule #21); rows are 128 B -> needs it.
#define ASTAGE(bf, kv)                                                              \
    {                                                                               \
        _Pragma("unroll") for (int i = 0; i < 2; ++i) {                             \
            int chunk = i * 256 + tid;                                              \
            int row = chunk >> 3;                                                   \
            int scir = (chunk & 7) ^ (row & 7);                                     \
            const u16* gk = Kh + ((kv) + row) * 64 + scir * 8;                      \
            const u16* gv = Vh + row * 1024 + (kv) + scir * 8;                      \
            u16* lk = &Ks[bf][0] + (i * 256 + wid * 64) * 8;                        \
            u16* lv = &Vs[bf][0] + (i * 256 + wid * 64) * 8;                        \
            __builtin_amdgcn_global_load_lds((const __attribute__((address_space(1))) u32*)gk, \
                                             (__attribute__((address_space(3))) u32*)lk, 16, 0, 0); \
            __builtin_amdgcn_global_load_lds((const __attribute__((address_space(1))) u32*)gv, \
                                             (__attribute__((address_space(3))) u32*)lv, 16, 0, 0); \
        }                                                                           \
    }

    ASTAGE(0, 0);
    __syncthreads();                   // vmcnt(0) drain: tile 0 ready

    int cur = 0;
    for (int t = 0; t < 16; ++t) {
        if (t < 15) ASTAGE(cur ^ 1, (t + 1) * 64);  // async, lands by next barrier
        const int kv = t * 64;
        const u16* Kb = &Ks[cur][0];
        const u16* Vb = &Vs[cur][0];

        // hoist this tile's mask + link loads (independent of MFMA chain)
        f32x4 m4[4], lk4[4];
        #pragma unroll
        for (int kt = 0; kt < 4; ++kt) {
            m4[kt]  = *(const f32x4*)(mk  + kv + kt * 16 + g * 4);
            lk4[kt] = *(const f32x4*)(lkq + kv + kt * 16 + g * 4);
        }

        // ---- QK^T + exp + link, one 16-key group at a time ----
        #pragma unroll
        for (int kt = 0; kt < 4; ++kt) {
            bf16x8 kf0 = *(const bf16x8*)(Kb + (kt * 16 + c) * 64 + ((g)     ^ c7) * 8);
            bf16x8 kf1 = *(const bf16x8*)(Kb + (kt * 16 + c) * 64 + ((4 + g) ^ c7) * 8);
            f32x4 sc = {};
            sc = __builtin_amdgcn_mfma_f32_16x16x32_bf16(kf0, qfx0, sc, 0, 0, 0);
            sc = __builtin_amdgcn_mfma_f32_16x16x32_bf16(kf1, qfx1, sc, 0, 0, 0);
            float e0 = __expf(sc[0] + m4[kt][0]);
            float e1 = __expf(sc[1] + m4[kt][1]);
            float e2 = __expf(sc[2] + m4[kt][2]);
            float e3 = __expf(sc[3] + m4[kt][3]);
            lsum += (e0 + e1) + (e2 + e3);
            U32x2 pw;
            pw.x = cvtpk(e0 * lk4[kt][0], e1 * lk4[kt][1]);
            pw.y = cvtpk(e2 * lk4[kt][2], e3 * lk4[kt][3]);
            // P write: row c, 8B-chunk (kt*4+g) ^ ((c&7)<<1)  [bank-uniform]
            *(U32x2*)(Pb + c * 64 + (((kt * 4 + g) ^ (c7 << 1)) * 4)) = pw;
        }
        // ---- PV: P from per-wave LDS (in-order DS pipe), V from staged tile ----
        __builtin_amdgcn_s_setprio(1);
        #pragma unroll
        for (int kk = 0; kk < 2; ++kk) {
            // P read: row c, 16B pair starting at chunk (kk*8+g*2) ^ ((c&7)<<1)
            bf16x8 pf = *(const bf16x8*)(Pb + c * 64 + (((kk * 8 + g * 2) ^ (c7 << 1)) * 4));
            #pragma unroll
            for (int dt = 0; dt < 4; ++dt) {
                bf16x8 vf = *(const bf16x8*)(Vb + (dt * 16 + c) * 64 + ((kk * 4 + g) ^ c7) * 8);
                ctx[dt] = __builtin_amdgcn_mfma_f32_16x16x32_bf16(pf, vf, ctx[dt], 0, 0, 0);
            }
        }
        __builtin_amdgcn_s_setprio(0);
        __syncthreads();               // all reads of buf[cur] done; stage drained
        cur ^= 1;
    }
#undef ASTAGE

    lsum += __shfl_xor(lsum, 16, 64);
    lsum += __shfl_xor(lsum, 32, 64);

    #pragma unroll
    for (int r = 0; r < 4; ++r) {
        float inv = 1.0f / __shfl(lsum, g * 4 + r, 16);
        int q = qbase + g * 4 + r;
        float* orow = out + (size_t)b * 1048576 + (size_t)q * 1024 + h * 64;
        #pragma unroll
        for (int dt = 0; dt < 4; ++dt)
            orow[dt * 16 + c] = ctx[dt][r] * inv;
    }
}

extern "C" void kernel_launch(void* const* d_in, const int* in_sizes, int n_in,
                              void* d_out, int out_size, void* d_ws, size_t ws_size,
                              hipStream_t stream)
{
    (void)in_sizes; (void)n_in; (void)out_size; (void)ws_size;
    const float* hs    = (const float*)d_in[0];
    const float* amask = (const float*)d_in[1];
    const float* link  = (const float*)d_in[2];
    const float* Wq    = (const float*)d_in[3];
    const float* bq    = (const float*)d_in[4];
    const float* Wk    = (const float*)d_in[5];
    const float* bk    = (const float*)d_in[6];
    const float* Wv    = (const float*)d_in[7];
    const float* bv    = (const float*)d_in[8];
    float* out = (float*)d_out;

    char* ws = (char*)d_ws;
    u16* hsb = (u16*)ws;                   // 8 MiB  [4096][1024] bf16
    u16* wb  = (u16*)(ws + (8u  << 20));   // 6 MiB  [3072][1024] bf16 (Wq|Wk|Wv)
    u16* Qb  = (u16*)(ws + (14u << 20));   // 8 MiB  [B,H,S,64]  (pre-scaled by 0.125)
    u16* Kb  = (u16*)(ws + (22u << 20));   // 8 MiB  [B,H,S,64]
    u16* Vtb = (u16*)(ws + (30u << 20));   // 8 MiB  [B,H,64,S]

    cvt_kernel<<<7168, 256, 0, stream>>>(hs, Wq, Wk, Wv, hsb, wb);
    qkv_gemm<<<dim3(24, 32), 256, 0, stream>>>(hsb, wb, bq, bk, bv, Qb, Kb, Vtb);
    attn_kernel<<<1024, 256, 0, stream>>>(Qb, Kb, Vtb, amask, link, out);
}